// Round 6
// baseline (185.998 us; speedup 1.0000x reference)
//
#include <hip/hip_runtime.h>
#include <hip/hip_bf16.h>
#include <math.h>

#define NROW 8192
#define DD   128
#define NT   64
#define TS   128
#define NPAIR 2080
#define BLOCK 512
#define NBLK  512

#define LOG_2PI 1.8378770664093453f
#define L2E     1.4426950408889634f
#define FP_SCALE 1099511627776.0   // 2^40 (fallback path only)

typedef __attribute__((ext_vector_type(8))) short bf16x8;
typedef __attribute__((ext_vector_type(4))) float f32x4;

// ---- ws byte layout ----
#define SQX_B 0
#define SQY_B 32768
#define BSUM_B 65536
#define COL_B 65792                          // NPAIR*384*4 = 3,194,880
#define ROW_B (COL_B + NPAIR*384*4)          // 1024 slots * 384 * 4 = 1,572,864
#define XB_B  (ROW_B + 1024*384*4)
#define YB_B  (XB_B + NROW*DD*2)
#define PRIMARY_NEED (YB_B + NROW*DD*2)      // ~9.03 MB
#define ACC_B COL_B                          // fallback overlays

__device__ __forceinline__ unsigned short f2bf(float f) {
    unsigned int x = __float_as_uint(f);
    unsigned int r = (x + 0x7fffu + ((x >> 16) & 1u)) >> 16;  // RNE
    return (unsigned short)r;
}
__device__ __forceinline__ float fexp2(float x) { return __builtin_amdgcn_exp2f(x); }

// ---------------- row squared norms (+ optional bf16 precopy) ----------------
template <bool PRE>
__global__ void sq_kernel(const float* __restrict__ X, const float* __restrict__ Y,
                          float* __restrict__ sqx, float* __restrict__ sqy,
                          unsigned short* __restrict__ XB, unsigned short* __restrict__ YB) {
    int tid  = threadIdx.x;
    int rowg = blockIdx.x * 8 + (tid >> 5);
    int lane = tid & 31;
    bool isX = rowg < NROW;
    const float* src = isX ? (X + (size_t)rowg * DD) : (Y + (size_t)(rowg - NROW) * DD);
    float4 v = reinterpret_cast<const float4*>(src)[lane];
    if (PRE) {
        unsigned int w0 = (unsigned int)f2bf(v.x) | ((unsigned int)f2bf(v.y) << 16);
        unsigned int w1 = (unsigned int)f2bf(v.z) | ((unsigned int)f2bf(v.w) << 16);
        unsigned short* dst = (isX ? XB + (size_t)rowg * DD
                                   : YB + (size_t)(rowg - NROW) * DD) + lane * 4;
        uint2 pk; pk.x = w0; pk.y = w1;
        *reinterpret_cast<uint2*>(dst) = pk;
    }
    float s = v.x * v.x + v.y * v.y + v.z * v.z + v.w * v.w;
#pragma unroll
    for (int m = 16; m; m >>= 1) s += __shfl_xor(s, m, 64);
    if (lane == 0) { if (isX) sqx[rowg] = s; else sqy[rowg - NROW] = s; }
}

// ================= PRIMARY =================

__device__ __forceinline__ void tile_of(int kp, int m, int& ti, int& tj) {
    int n1 = 64 - kp;                 // tiles in row kp
    if (m < n1) { ti = kp;      tj = kp + m; }
    else        { ti = 63 - kp; tj = 63 - kp + (m - n1); }
}
__device__ __forceinline__ int rank_of(int ti, int tj) {
    return ti * 64 - (ti * (ti - 1)) / 2 + (tj - ti);
}

struct Stg { uint4 v[8]; float sq; };

__device__ __forceinline__ void issue_stage(const unsigned short* __restrict__ XB,
                                            const unsigned short* __restrict__ YB,
                                            const float* __restrict__ sqx,
                                            const float* __restrict__ sqy,
                                            int tj, int tid, int lane, Stg& s) {
    int mat   = (tid >> 6) >> 2;      // 0: X, 1: Y
    int rband = ((tid >> 6) & 3) * 32;
    const unsigned short* gb = (mat ? YB : XB) + (size_t)(tj * TS) * DD;
#pragma unroll
    for (int i = 0; i < 8; ++i) {
        int row = rband + i * 4 + (lane >> 4);
        s.v[i] = *reinterpret_cast<const uint4*>(gb + (size_t)row * DD + (lane & 15) * 8);
    }
    if (tid < 256) {
        const float* g = (tid < 128) ? (sqx + tj * TS + tid) : (sqy + tj * TS + (tid - 128));
        s.sq = *g;
    }
}
__device__ __forceinline__ void write_stage(int tid, int lane, const Stg& s,
                                            unsigned short (*buf)[TS][DD], float (*sqjb)[TS]) {
    int mat   = (tid >> 6) >> 2;
    int rband = ((tid >> 6) & 3) * 32;
#pragma unroll
    for (int i = 0; i < 8; ++i) {
        int row = rband + i * 4 + (lane >> 4);
        int sl  = (lane & 15) ^ (row & 7);
        *reinterpret_cast<uint4*>(&buf[mat][row][sl * 8]) = s.v[i];
    }
    if (tid < 256) sqjb[tid >> 7][tid & 127] = s.sq;
}

__device__ __forceinline__ void load_A(const unsigned short* __restrict__ XB,
                                       const unsigned short* __restrict__ YB,
                                       const float* __restrict__ sqx,
                                       const float* __restrict__ sqy,
                                       int ti, int wr, int lane, float cx2, float cy2,
                                       bf16x8 (&afx)[2][4], bf16x8 (&afy)[2][4],
                                       float (&axipm)[2][4], float (&ayipm)[2][4]) {
    int i0 = ti * TS;
#pragma unroll
    for (int rf = 0; rf < 2; ++rf) {
        int rowa = i0 + wr * 32 + rf * 16 + (lane & 15);
#pragma unroll
        for (int kk = 0; kk < 4; ++kk) {
            size_t off = (size_t)rowa * DD + kk * 32 + (lane >> 4) * 8;
            afx[rf][kk] = *reinterpret_cast<const bf16x8*>(XB + off);
            afy[rf][kk] = *reinterpret_cast<const bf16x8*>(YB + off);
        }
#pragma unroll
        for (int reg = 0; reg < 4; ++reg) {
            int rowc = i0 + wr * 32 + rf * 16 + ((lane >> 4) << 2) + reg;
            axipm[rf][reg] = cx2 * sqx[rowc];
            ayipm[rf][reg] = cy2 * sqy[rowc];
        }
    }
}

// tx = cx2*d2x computed as fmaf(gx, -2*cx2, axipm + bxjpm); ex = exp2(tx)
template <bool SAME, bool DIAG>
__device__ __forceinline__ void do_combine(const f32x4 (&ax)[2][4], const f32x4 (&ay)[2][4],
                                           const float (&axipm)[2][4], const float (&ayipm)[2][4],
                                           const float (&bxj)[4], const float (&byj)[4],
                                           float m2cx, float m2cy, float rx, float ry,
                                           float (&prow)[2][4][3], float (&pcol)[4][3],
                                           int wr, int wc, int lane) {
#pragma unroll
    for (int cf = 0; cf < 4; ++cf) {
        const float bx = bxj[cf], by = byj[cf];
        const int coll = wc * 64 + cf * 16 + (lane & 15);
#pragma unroll
        for (int rf = 0; rf < 2; ++rf) {
#pragma unroll
            for (int reg = 0; reg < 4; ++reg) {
                float tx = fmaf(ax[rf][cf][reg], m2cx, axipm[rf][reg] + bx);
                float ty = fmaf(ay[rf][cf][reg], m2cy, ayipm[rf][reg] + by);
                float ex = fexp2(tx);
                float ey = fexp2(ty);
                float ej = SAME ? (ex * ey) : fexp2(fmaf(tx, rx, ty * ry));
                if (DIAG) {
                    int rowl = wr * 32 + rf * 16 + ((lane >> 4) << 2) + reg;
                    bool dg = (rowl == coll);
                    ex = dg ? 1.f : ex;  ey = dg ? 1.f : ey;  ej = dg ? 1.f : ej;
                }
                prow[rf][reg][0] += ex; prow[rf][reg][1] += ey; prow[rf][reg][2] += ej;
                pcol[cf][0] += ex;      pcol[cf][1] += ey;      pcol[cf][2] += ej;
            }
        }
    }
}

// LDS (148 KB) already limits to 1 workgroup/CU = 2 waves/EU. Pin the backend's
// occupancy TARGET to exactly that, so the VGPR budget becomes 512/2 = 256 and it
// stops spilling to chase 4 waves/EU (rounds 4/5: VGPR capped at 128 -> 288 MB of
// scratch write traffic = the whole kernel's runtime).
__launch_bounds__(BLOCK)
__attribute__((amdgpu_waves_per_eu(2, 2)))
__global__ void kde_primary(const unsigned short* __restrict__ XB,
                            const unsigned short* __restrict__ YB,
                            const float* __restrict__ sjp, const float* __restrict__ sxp,
                            const float* __restrict__ syp,
                            const float* __restrict__ sqx, const float* __restrict__ sqy,
                            float* __restrict__ COL, float* __restrict__ ROWS) {
    __shared__ unsigned short buf[2][2][TS][DD];   // 128 KB dbuf {X,Y}
    __shared__ float sqjb[2][2][TS];               // 2 KB
    __shared__ float colred[2][4][TS][3];          // 12 KB
    __shared__ float rowred[2][2][TS][3];          // 6 KB

    const int tid  = threadIdx.x;
    const int lane = tid & 63;
    const int wid  = tid >> 6;
    const int wr   = wid >> 1;     // 0..3 : 32-row band
    const int wc   = wid & 1;      // 0..1 : 64-col half

    // block -> (kp, chunk); XCD-grouped: blocks with same kp land on same XCD
    const int bid = blockIdx.x;
    const int x   = bid & 7, n = bid >> 3;
    const int kp  = x * 4 + (n & 3);     // [0,32)
    const int cch = n >> 2;              // [0,16)
    const int t0  = (65 * cch) >> 4;
    const int t1  = (65 * (cch + 1)) >> 4;

    const float sxv = *sxp, syv = *syp, sjv = *sjp;
    const float cx2 = -0.5f * L2E / (sxv * sxv);
    const float cy2 = -0.5f * L2E / (syv * syv);
    const float cj2 = -0.5f * L2E / (sjv * sjv);
    const bool  same = (cx2 == cy2) && (cy2 == cj2);
    const float m2cx = -2.f * cx2, m2cy = -2.f * cy2;
    const float rx = cj2 / cx2, ry = cj2 / cy2;

    bf16x8 afx[2][4], afy[2][4];
    float  axipm[2][4], ayipm[2][4];
    int curti = -1;

    float prow[2][4][3];
#pragma unroll
    for (int a = 0; a < 2; ++a)
#pragma unroll
        for (int b = 0; b < 4; ++b)
#pragma unroll
            for (int c = 0; c < 3; ++c) prow[a][b][c] = 0.f;

    Stg stg;
    {   // prologue: stage first tile
        int ti0, tj0; tile_of(kp, t0, ti0, tj0);
        issue_stage(XB, YB, sqx, sqy, tj0, tid, lane, stg);
        write_stage(tid, lane, stg, buf[0], sqjb[0]);
    }
    __syncthreads();

    int p = 0;
    bool w0 = false, w1 = false;

    for (int m = t0; m < t1; ++m) {
        int ti, tj; tile_of(kp, m, ti, tj);
        if (ti != curti) {
            load_A(XB, YB, sqx, sqy, ti, wr, lane, cx2, cy2, afx, afy, axipm, ayipm);
            curti = ti;
        }
        const bool last = (m + 1 >= t1);
        int tin = -1, tjn = -1;
        if (!last) {
            tile_of(kp, m + 1, tin, tjn);
            issue_stage(XB, YB, sqx, sqy, tjn, tid, lane, stg);   // prefetch next tile -> regs
        }

        // ---- MFMA: Gx, Gy on buf[p] ----
        f32x4 ax[2][4], ay[2][4];
#pragma unroll
        for (int rf = 0; rf < 2; ++rf)
#pragma unroll
            for (int cf = 0; cf < 4; ++cf) {
                ax[rf][cf] = (f32x4){0.f, 0.f, 0.f, 0.f};
                ay[rf][cf] = (f32x4){0.f, 0.f, 0.f, 0.f};
            }
#pragma unroll
        for (int kk = 0; kk < 4; ++kk) {
            bf16x8 bfx[4], bfy[4];
#pragma unroll
            for (int cf = 0; cf < 4; ++cf) {
                int rb = wc * 64 + cf * 16 + (lane & 15);
                int sl = (kk * 4 + (lane >> 4)) ^ (rb & 7);
                bfx[cf] = *reinterpret_cast<const bf16x8*>(&buf[p][0][rb][sl * 8]);
                bfy[cf] = *reinterpret_cast<const bf16x8*>(&buf[p][1][rb][sl * 8]);
            }
#pragma unroll
            for (int cf = 0; cf < 4; ++cf)
#pragma unroll
                for (int rf = 0; rf < 2; ++rf) {
                    ax[rf][cf] = __builtin_amdgcn_mfma_f32_16x16x32_bf16(afx[rf][kk], bfx[cf], ax[rf][cf], 0, 0, 0);
                    ay[rf][cf] = __builtin_amdgcn_mfma_f32_16x16x32_bf16(afy[rf][kk], bfy[cf], ay[rf][cf], 0, 0, 0);
                }
        }

        // ---- write prefetched tile into the OTHER buffer (frees stg regs before combine) ----
        if (!last) write_stage(tid, lane, stg, buf[p ^ 1], sqjb[p ^ 1]);

        // per-tile col constants from LDS (after write_stage: shortens stg liveness)
        float bxj[4], byj[4];
#pragma unroll
        for (int cf = 0; cf < 4; ++cf) {
            int coll = wc * 64 + cf * 16 + (lane & 15);
            bxj[cf] = cx2 * sqjb[p][0][coll];
            byj[cf] = cy2 * sqjb[p][1][coll];
        }

        // ---- combine ----
        float pcol[4][3];
#pragma unroll
        for (int a = 0; a < 4; ++a)
#pragma unroll
            for (int c = 0; c < 3; ++c) pcol[a][c] = 0.f;

        const bool diag = (ti == tj);
        if (same) { if (diag) do_combine<true , true >(ax, ay, axipm, ayipm, bxj, byj, m2cx, m2cy, rx, ry, prow, pcol, wr, wc, lane);
                    else      do_combine<true , false>(ax, ay, axipm, ayipm, bxj, byj, m2cx, m2cy, rx, ry, prow, pcol, wr, wc, lane); }
        else      { if (diag) do_combine<false, true >(ax, ay, axipm, ayipm, bxj, byj, m2cx, m2cy, rx, ry, prow, pcol, wr, wc, lane);
                    else      do_combine<false, false>(ax, ay, axipm, ayipm, bxj, byj, m2cx, m2cy, rx, ry, prow, pcol, wr, wc, lane); }

        // ---- col partials -> colred[p] ----
#pragma unroll
        for (int cf = 0; cf < 4; ++cf)
#pragma unroll
            for (int ch = 0; ch < 3; ++ch) {
                float v = pcol[cf][ch];
                v += __shfl_xor(v, 16, 64);
                v += __shfl_xor(v, 32, 64);
                if (lane < 16) colred[p][wr][wc * 64 + cf * 16 + lane][ch] = v;
            }

        // ---- row flush (end of an i-row or end of chunk) ----
        const bool rowdone = last || (tin != ti);
        if (rowdone) {
#pragma unroll
            for (int rf = 0; rf < 2; ++rf)
#pragma unroll
                for (int reg = 0; reg < 4; ++reg)
#pragma unroll
                    for (int ch = 0; ch < 3; ++ch) {
                        float v = prow[rf][reg][ch];
                        v += __shfl_xor(v, 1, 64);
                        v += __shfl_xor(v, 2, 64);
                        v += __shfl_xor(v, 4, 64);
                        v += __shfl_xor(v, 8, 64);
                        if ((lane & 15) == 0)
                            rowred[p][wc][wr * 32 + rf * 16 + ((lane >> 4) << 2) + reg][ch] = v;
                        prow[rf][reg][ch] = 0.f;
                    }
        }

        __syncthreads();

        // ---- post-barrier: private-slot stores (no atomics) ----
        if (ti != tj && tid < 384) {
            int ch = tid >> 7, col = tid & 127;
            float v = colred[p][0][col][ch] + colred[p][1][col][ch]
                    + colred[p][2][col][ch] + colred[p][3][col][ch];
            size_t rk = (size_t)rank_of(ti, tj);
            COL[(rk * 3 + ch) * 128 + col] = v;
        }
        if (rowdone) {
            int which = (ti == kp) ? 0 : 1;
            if (tid < 384) {
                int ch = tid >> 7, row = tid & 127;
                size_t slot = ((size_t)(kp * 16 + cch) * 2 + which);
                ROWS[(slot * 3 + ch) * 128 + row] = rowred[p][0][row][ch] + rowred[p][1][row][ch];
            }
            if (which == 0) w0 = true; else w1 = true;
        }
        p ^= 1;
    }

    // zero-fill the untouched row slot so lp can gather unconditionally
    if (!w0 && tid < 384) {
        int ch = tid >> 7, row = tid & 127;
        ROWS[(((size_t)(kp * 16 + cch) * 2 + 0) * 3 + ch) * 128 + row] = 0.f;
    }
    if (!w1 && tid < 384) {
        int ch = tid >> 7, row = tid & 127;
        ROWS[(((size_t)(kp * 16 + cch) * 2 + 1) * 3 + ch) * 128 + row] = 0.f;
    }
}

__global__ void lp_primary(const float* __restrict__ sjp, const float* __restrict__ sxp,
                           const float* __restrict__ syp,
                           const float* __restrict__ COL, const float* __restrict__ ROWS,
                           float* __restrict__ bsum) {
    int b = blockIdx.x;    // row-tile [0,64)
    int t = threadIdx.x;   // 128
    float S0 = 0.f, S1 = 0.f, S2 = 0.f;
    int kp2 = (b < 32) ? b : 63 - b;
    int which = (b < 32) ? 0 : 1;
    for (int c = 0; c < 16; ++c) {
        size_t slot = ((size_t)(kp2 * 16 + c) * 2 + which) * 3;
        S0 += ROWS[(slot + 0) * 128 + t];
        S1 += ROWS[(slot + 1) * 128 + t];
        S2 += ROWS[(slot + 2) * 128 + t];
    }
    for (int ti = 0; ti < b; ++ti) {
        size_t rk = (size_t)(ti * 64 - (ti * (ti - 1)) / 2 + (b - ti));
        S0 += COL[(rk * 3 + 0) * 128 + t];
        S1 += COL[(rk * 3 + 1) * 128 + t];
        S2 += COL[(rk * 3 + 2) * 128 + t];
    }
    float sx = *sxp, sy = *syp, sj = *sjp;
    float logN = logf((float)NROW);
    float lpx = logf(S0) - (float)DD * logf(sx) - 0.5f * (float)DD * LOG_2PI - logN;
    float lpy = logf(S1) - (float)DD * logf(sy) - 0.5f * (float)DD * LOG_2PI - logN;
    float lpj = logf(S2) - 2.0f * (float)DD * logf(sj) - (float)DD * LOG_2PI - logN;
    float I = expf(lpj) * (lpj - lpx - lpy);
#pragma unroll
    for (int m = 1; m < 64; m <<= 1) I += __shfl_xor(I, m, 64);
    __shared__ float w0s[2];
    if ((t & 63) == 0) w0s[t >> 6] = I;
    __syncthreads();
    if (t == 0) bsum[b] = w0s[0] + w0s[1];
}

__global__ void final_reduce(const float* __restrict__ bsum, float* __restrict__ out) {
    int t = threadIdx.x;   // 64
    float v = bsum[t];
#pragma unroll
    for (int m = 1; m < 64; m <<= 1) v += __shfl_xor(v, m, 64);
    if (t == 0) out[0] = -v;
}

// ================= FALLBACK (round-2, proven; only if ws too small) =================
template <bool SAME>
__device__ __forceinline__ void fb_combine(const f32x4 (&ax)[4][2], const f32x4 (&ay)[4][2],
                                           const float (&sq)[4][TS],
                                           float (&rowred)[4][TS][3], float (&colred)[2][TS][3],
                                           int wr, int wc, int lane,
                                           float cx2, float cy2, float cj2) {
    float pcol[2][3] = {{0.f,0.f,0.f},{0.f,0.f,0.f}};
#pragma unroll
    for (int rf = 0; rf < 4; ++rf) {
        float prow[4][3] = {{0.f,0.f,0.f},{0.f,0.f,0.f},{0.f,0.f,0.f},{0.f,0.f,0.f}};
        float sxi[4], syi[4];
#pragma unroll
        for (int reg = 0; reg < 4; ++reg) {
            int row = wr*64 + rf*16 + ((lane>>4)<<2) + reg;
            sxi[reg] = sq[0][row]; syi[reg] = sq[1][row];
        }
#pragma unroll
        for (int cf = 0; cf < 2; ++cf) {
            int col = wc*32 + cf*16 + (lane & 15);
            float qx = sq[2][col], qy = sq[3][col];
#pragma unroll
            for (int reg = 0; reg < 4; ++reg) {
                float gx = ax[rf][cf][reg], gy = ay[rf][cf][reg];
                float d2x = fmaxf(fmaf(-2.f, gx, sxi[reg] + qx), 0.f);
                float d2y = fmaxf(fmaf(-2.f, gy, syi[reg] + qy), 0.f);
                float ex = fexp2(d2x * cx2);
                float ey = fexp2(d2y * cy2);
                float ej = SAME ? (ex * ey) : fexp2(fmaf(d2y, cj2, d2x * cj2));
                prow[reg][0] += ex; prow[reg][1] += ey; prow[reg][2] += ej;
                pcol[cf][0]  += ex; pcol[cf][1]  += ey; pcol[cf][2]  += ej;
            }
        }
#pragma unroll
        for (int reg = 0; reg < 4; ++reg)
#pragma unroll
            for (int ch = 0; ch < 3; ++ch) {
                float v = prow[reg][ch];
                v += __shfl_xor(v, 1, 64); v += __shfl_xor(v, 2, 64);
                v += __shfl_xor(v, 4, 64); v += __shfl_xor(v, 8, 64);
                if ((lane & 15) == 0)
                    rowred[wc][wr*64 + rf*16 + ((lane>>4)<<2) + reg][ch] = v;
            }
    }
#pragma unroll
    for (int cf = 0; cf < 2; ++cf)
#pragma unroll
        for (int ch = 0; ch < 3; ++ch) {
            float v = pcol[cf][ch];
            v += __shfl_xor(v, 16, 64); v += __shfl_xor(v, 32, 64);
            if (lane < 16) colred[wr][wc*32 + cf*16 + lane][ch] = v;
        }
}

__launch_bounds__(BLOCK)
__global__ void kde_fb(const float* __restrict__ X, const float* __restrict__ Y,
                       const float* __restrict__ sjp, const float* __restrict__ sxp,
                       const float* __restrict__ syp,
                       unsigned long long* __restrict__ acc,
                       const float* __restrict__ sqx, const float* __restrict__ sqy) {
    __shared__ unsigned short T[4][TS][DD];
    __shared__ float sq[4][TS];
    __shared__ float rowred[4][TS][3];
    __shared__ float colred[2][TS][3];

    const int tid  = threadIdx.x;
    const int lane = tid & 63;
    const int wid  = tid >> 6;
    const int wr   = wid >> 2;
    const int wc   = wid & 3;

    int b = (blockIdx.x & 7) * (NPAIR / 8) + (blockIdx.x >> 3);
    int ti = 0, rem = b;
    while (rem >= NT - ti) { rem -= NT - ti; ++ti; }
    int tj = ti + rem;
    const int i0 = ti * TS, j0 = tj * TS;

    const float sxv = *sxp, syv = *syp, sjv = *sjp;
    const float cx2 = -0.5f * L2E / (sxv * sxv);
    const float cy2 = -0.5f * L2E / (syv * syv);
    const float cj2 = -0.5f * L2E / (sjv * sjv);
    const bool samesig = (cx2 == cy2) && (cy2 == cj2);

    for (int c = tid; c < 8192; c += BLOCK) {
        int t = c >> 11, row = (c >> 4) & 127, col8 = c & 15;
        const float* base =
            (t == 0) ? X + (size_t)i0 * DD : (t == 1) ? Y + (size_t)i0 * DD :
            (t == 2) ? X + (size_t)j0 * DD : Y + (size_t)j0 * DD;
        const float4* s4 = reinterpret_cast<const float4*>(base + row * DD + col8 * 8);
        float4 a = s4[0], bb = s4[1];
        unsigned int w0 = (unsigned int)f2bf(a.x)  | ((unsigned int)f2bf(a.y)  << 16);
        unsigned int w1 = (unsigned int)f2bf(a.z)  | ((unsigned int)f2bf(a.w)  << 16);
        unsigned int w2 = (unsigned int)f2bf(bb.x) | ((unsigned int)f2bf(bb.y) << 16);
        unsigned int w3 = (unsigned int)f2bf(bb.z) | ((unsigned int)f2bf(bb.w) << 16);
        uint4 pk = make_uint4(w0, w1, w2, w3);
        int sl = (col8 ^ (row & 7)) << 3;
        *reinterpret_cast<uint4*>(&T[t][row][sl]) = pk;
    }
    {
        int t = tid >> 7, r = tid & 127;
        const float* s = (t == 0) ? sqx + i0 : (t == 1) ? sqy + i0
                       : (t == 2) ? sqx + j0 : sqy + j0;
        sq[t][r] = s[r];
    }
    __syncthreads();

    f32x4 ax[4][2], ay[4][2];
#pragma unroll
    for (int rf = 0; rf < 4; ++rf)
#pragma unroll
        for (int cf = 0; cf < 2; ++cf) {
            ax[rf][cf] = (f32x4){0.f,0.f,0.f,0.f};
            ay[rf][cf] = (f32x4){0.f,0.f,0.f,0.f};
        }
#pragma unroll
    for (int kk = 0; kk < 4; ++kk) {
        const int k0 = kk * 4 + (lane >> 4);
        bf16x8 afx[4], afy[4], bfx[2], bfy[2];
#pragma unroll
        for (int rf = 0; rf < 4; ++rf) {
            int r  = wr * 64 + rf * 16 + (lane & 15);
            int sl = (k0 ^ (r & 7)) << 3;
            afx[rf] = *reinterpret_cast<const bf16x8*>(&T[0][r][sl]);
            afy[rf] = *reinterpret_cast<const bf16x8*>(&T[1][r][sl]);
        }
#pragma unroll
        for (int cf = 0; cf < 2; ++cf) {
            int r  = wc * 32 + cf * 16 + (lane & 15);
            int sl = (k0 ^ (r & 7)) << 3;
            bfx[cf] = *reinterpret_cast<const bf16x8*>(&T[2][r][sl]);
            bfy[cf] = *reinterpret_cast<const bf16x8*>(&T[3][r][sl]);
        }
#pragma unroll
        for (int rf = 0; rf < 4; ++rf)
#pragma unroll
            for (int cf = 0; cf < 2; ++cf) {
                ax[rf][cf] = __builtin_amdgcn_mfma_f32_16x16x32_bf16(afx[rf], bfx[cf], ax[rf][cf], 0, 0, 0);
                ay[rf][cf] = __builtin_amdgcn_mfma_f32_16x16x32_bf16(afy[rf], bfy[cf], ay[rf][cf], 0, 0, 0);
            }
    }

    if (samesig) fb_combine<true >(ax, ay, sq, rowred, colred, wr, wc, lane, cx2, cy2, cj2);
    else         fb_combine<false>(ax, ay, sq, rowred, colred, wr, wc, lane, cx2, cy2, cj2);
    __syncthreads();

    if (tid < TS) {
        int r = tid;
#pragma unroll
        for (int ch = 0; ch < 3; ++ch) {
            float v = rowred[0][r][ch] + rowred[1][r][ch] + rowred[2][r][ch] + rowred[3][r][ch];
            atomicAdd(&acc[(size_t)(i0 + r) * 3 + ch],
                      (unsigned long long)(long long)((double)v * FP_SCALE));
        }
    } else if (tid < 2 * TS && ti != tj) {
        int r = tid - TS;
#pragma unroll
        for (int ch = 0; ch < 3; ++ch) {
            float v = colred[0][r][ch] + colred[1][r][ch];
            atomicAdd(&acc[(size_t)(j0 + r) * 3 + ch],
                      (unsigned long long)(long long)((double)v * FP_SCALE));
        }
    }
}

__global__ void lp_fb(const float* __restrict__ sjp, const float* __restrict__ sxp,
                      const float* __restrict__ syp,
                      const unsigned long long* __restrict__ acc,
                      float* __restrict__ bsum) {
    int b = blockIdx.x, t = threadIdx.x;
    size_t row = (size_t)b * 128 + t;
    const double INV = 1.0 / FP_SCALE;
    float S0 = (float)((double)acc[row * 3 + 0] * INV);
    float S1 = (float)((double)acc[row * 3 + 1] * INV);
    float S2 = (float)((double)acc[row * 3 + 2] * INV);
    float sx = *sxp, sy = *syp, sj = *sjp;
    float logN = logf((float)NROW);
    float lpx = logf(S0) - (float)DD * logf(sx) - 0.5f * (float)DD * LOG_2PI - logN;
    float lpy = logf(S1) - (float)DD * logf(sy) - 0.5f * (float)DD * LOG_2PI - logN;
    float lpj = logf(S2) - 2.0f * (float)DD * logf(sj) - (float)DD * LOG_2PI - logN;
    float I = expf(lpj) * (lpj - lpx - lpy);
#pragma unroll
    for (int m = 1; m < 64; m <<= 1) I += __shfl_xor(I, m, 64);
    __shared__ float w0[2];
    if ((t & 63) == 0) w0[t >> 6] = I;
    __syncthreads();
    if (t == 0) bsum[b] = w0[0] + w0[1];
}

extern "C" void kernel_launch(void* const* d_in, const int* in_sizes, int n_in,
                              void* d_out, int out_size, void* d_ws, size_t ws_size,
                              hipStream_t stream) {
    (void)in_sizes; (void)n_in; (void)out_size;
    const float* X  = (const float*)d_in[0];
    const float* Y  = (const float*)d_in[1];
    const float* sj = (const float*)d_in[2];
    const float* sx = (const float*)d_in[3];
    const float* sy = (const float*)d_in[4];
    float* out = (float*)d_out;
    char*  w   = (char*)d_ws;

    float* SQX  = (float*)(w + SQX_B);
    float* SQY  = (float*)(w + SQY_B);
    float* BSUM = (float*)(w + BSUM_B);
    float* COLS = (float*)(w + COL_B);
    float* ROWS = (float*)(w + ROW_B);
    unsigned short* XB = (unsigned short*)(w + XB_B);
    unsigned short* YB = (unsigned short*)(w + YB_B);

    if (ws_size >= (size_t)PRIMARY_NEED) {
        sq_kernel<true ><<<dim3(2048), dim3(256), 0, stream>>>(X, Y, SQX, SQY, XB, YB);
        kde_primary<<<dim3(NBLK), dim3(BLOCK), 0, stream>>>(XB, YB, sj, sx, sy, SQX, SQY, COLS, ROWS);
        lp_primary<<<dim3(64), dim3(128), 0, stream>>>(sj, sx, sy, COLS, ROWS, BSUM);
    } else {
        unsigned long long* ACC = (unsigned long long*)(w + ACC_B);
        hipMemsetAsync(w + ACC_B, 0, NROW * 3 * sizeof(unsigned long long), stream);
        sq_kernel<false><<<dim3(2048), dim3(256), 0, stream>>>(X, Y, SQX, SQY, XB, YB);
        kde_fb<<<dim3(NPAIR), dim3(BLOCK), 0, stream>>>(X, Y, sj, sx, sy, ACC, SQX, SQY);
        lp_fb<<<dim3(64), dim3(128), 0, stream>>>(sj, sx, sy, ACC, BSUM);
    }
    final_reduce<<<dim3(1), dim3(64), 0, stream>>>(BSUM, out);
}

// Round 7
// 135.745 us; speedup vs baseline: 1.3702x; 1.3702x over previous
//
#include <hip/hip_runtime.h>
#include <hip/hip_bf16.h>
#include <math.h>

#define NROW 8192
#define DD   128
#define TI   128          // i-tile rows (primary)
#define TJ   64           // j-tile cols (primary)
#define BLOCK 512
#define NBLK  512
#define NCOLSLOT 4032     // sum over I of (126-2I)

// fallback geometry (round-2 proven)
#define NT   64
#define TS   128
#define NPAIR 2080

#define LOG_2PI 1.8378770664093453f
#define L2E     1.4426950408889634f
#define FP_SCALE 1099511627776.0   // 2^40 (fallback only)

typedef __attribute__((ext_vector_type(8))) short bf16x8;
typedef __attribute__((ext_vector_type(4))) float f32x4;

// ---- ws byte layout ----
#define SQX_B 0
#define SQY_B 32768
#define BSUM_B 65536
#define COL_B 65792                              // 4032*3*64*4 = 3,096,576
#define ROW_B (COL_B + NCOLSLOT*3*64*4)          // 1024*3*128*4 = 1,572,864
#define XB_B  (ROW_B + 1024*3*128*4)
#define YB_B  (XB_B + NROW*DD*2)
#define PRIMARY_NEED (YB_B + NROW*DD*2)          // ~8.93 MB
#define ACC_B COL_B                              // fallback overlays

__device__ __forceinline__ unsigned short f2bf(float f) {
    unsigned int x = __float_as_uint(f);
    unsigned int r = (x + 0x7fffu + ((x >> 16) & 1u)) >> 16;  // RNE
    return (unsigned short)r;
}
__device__ __forceinline__ float fexp2(float x) { return __builtin_amdgcn_exp2f(x); }

// ---------------- row squared norms (+ optional bf16 precopy) ----------------
template <bool PRE>
__global__ void sq_kernel(const float* __restrict__ X, const float* __restrict__ Y,
                          float* __restrict__ sqx, float* __restrict__ sqy,
                          unsigned short* __restrict__ XB, unsigned short* __restrict__ YB) {
    int tid  = threadIdx.x;
    int rowg = blockIdx.x * 8 + (tid >> 5);
    int lane = tid & 31;
    bool isX = rowg < NROW;
    const float* src = isX ? (X + (size_t)rowg * DD) : (Y + (size_t)(rowg - NROW) * DD);
    float4 v = reinterpret_cast<const float4*>(src)[lane];
    if (PRE) {
        unsigned int w0 = (unsigned int)f2bf(v.x) | ((unsigned int)f2bf(v.y) << 16);
        unsigned int w1 = (unsigned int)f2bf(v.z) | ((unsigned int)f2bf(v.w) << 16);
        unsigned short* dst = (isX ? XB + (size_t)rowg * DD
                                   : YB + (size_t)(rowg - NROW) * DD) + lane * 4;
        uint2 pk; pk.x = w0; pk.y = w1;
        *reinterpret_cast<uint2*>(dst) = pk;
    }
    float s = v.x * v.x + v.y * v.y + v.z * v.z + v.w * v.w;
#pragma unroll
    for (int m = 16; m; m >>= 1) s += __shfl_xor(s, m, 64);
    if (lane == 0) { if (isX) sqx[rowg] = s; else sqy[rowg - NROW] = s; }
}

// ================= PRIMARY (v7: A-in-LDS, B-from-L2, no spill) =================

// stage the 128-row i-tile (both mats, 64 KB) into LDS, XOR-swizzled 16B slots.
// Transient registers only (nothing else live at i-switch).
__device__ __forceinline__ void stage_A(const unsigned short* __restrict__ XB,
                                        const unsigned short* __restrict__ YB,
                                        int i0, int wid, int lane,
                                        unsigned short (*A)[TI][DD]) {
    int mat   = wid >> 2;
    int rband = (wid & 3) * 32;
    const unsigned short* gb = (mat ? YB : XB) + (size_t)i0 * DD;
#pragma unroll
    for (int i = 0; i < 8; ++i) {
        int row = rband + i * 4 + (lane >> 4);
        uint4 v = *reinterpret_cast<const uint4*>(gb + (size_t)row * DD + (lane & 15) * 8);
        int sl = (lane & 15) ^ (row & 7);
        *reinterpret_cast<uint4*>(&A[mat][row][sl * 8]) = v;
    }
}

// MODE: SAME = sigmas equal (ej = ex*ey); DIAG = tile straddles the diagonal
template <bool SAME, bool DIAG>
__device__ __forceinline__ void do_combine(const f32x4 (&ax)[2][2], const f32x4 (&ay)[2][2],
                                           const f32x4 (&six)[2], const f32x4 (&siy)[2],
                                           const float (&sxj)[2], const float (&syj)[2],
                                           float cx2, float cy2, float m2cx, float m2cy,
                                           float rx, float ry, int dj,
                                           float (&prow)[2][4][3], float (&pcol)[2][3],
                                           int wr, int wc, int lane) {
#pragma unroll
    for (int rf = 0; rf < 2; ++rf) {
#pragma unroll
        for (int cf = 0; cf < 2; ++cf) {
            const float bx = cx2 * sxj[cf];
            const float by = cy2 * syj[cf];
            const int coll = wc * 32 + cf * 16 + (lane & 15);
#pragma unroll
            for (int reg = 0; reg < 4; ++reg) {
                float tx = fmaf(ax[rf][cf][reg], m2cx, fmaf(cx2, six[rf][reg], bx));
                float ty = fmaf(ay[rf][cf][reg], m2cy, fmaf(cy2, siy[rf][reg], by));
                float ex = fexp2(tx);
                float ey = fexp2(ty);
                float ej = SAME ? (ex * ey) : fexp2(fmaf(tx, rx, ty * ry));
                if (DIAG) {
                    int rowl = wr * 32 + rf * 16 + ((lane >> 4) << 2) + reg;
                    bool dg = (rowl == coll + dj);
                    ex = dg ? 1.f : ex;  ey = dg ? 1.f : ey;  ej = dg ? 1.f : ej;
                }
                prow[rf][reg][0] += ex; prow[rf][reg][1] += ey; prow[rf][reg][2] += ej;
                pcol[cf][0] += ex;      pcol[cf][1] += ey;      pcol[cf][2] += ej;
            }
        }
    }
}

__launch_bounds__(BLOCK)
__global__ void kde_primary(const unsigned short* __restrict__ XB,
                            const unsigned short* __restrict__ YB,
                            const float* __restrict__ sjp, const float* __restrict__ sxp,
                            const float* __restrict__ syp,
                            const float* __restrict__ sqx, const float* __restrict__ sqy,
                            float* __restrict__ COL, float* __restrict__ ROWS) {
    __shared__ unsigned short Alds[2][TI][DD];   // 64 KB, swizzled
    __shared__ float sqi[2][TI];                 // 1 KB
    __shared__ float colred[2][4][TJ][3];        // 6 KB (dbuf)
    __shared__ float rowred[2][TI][3];           // 3 KB
    // total ~74 KB -> 2 blocks/CU

    const int tid  = threadIdx.x;
    const int lane = tid & 63;
    const int wid  = tid >> 6;
    const int wr   = wid >> 1;     // 0..3 : 32-row band of the 128-row i-tile
    const int wc   = wid & 1;      // 0..1 : 32-col half of the 64-col j-tile

    // block -> (kp, chunk). Row kp (128-2kp j-tiles) + row 63-kp (2kp+2) = 130 tiles.
    const int bid = blockIdx.x;
    const int kp  = (bid & 7) * 4 + ((bid >> 3) & 3);   // [0,32) ; bid&7 = XCD
    const int cch = bid >> 5;                           // [0,16)
    const int t0  = (130 * cch) >> 4;
    const int t1  = (130 * (cch + 1)) >> 4;

    const float sxv = *sxp, syv = *syp, sjv = *sjp;
    const float cx2 = -0.5f * L2E / (sxv * sxv);
    const float cy2 = -0.5f * L2E / (syv * syv);
    const float cj2 = -0.5f * L2E / (sjv * sjv);
    const bool  same = (cx2 == cy2) && (cy2 == cj2);
    const float m2cx = -2.f * cx2, m2cy = -2.f * cy2;
    const float rx = cj2 / cx2, ry = cj2 / cy2;

    float prow[2][4][3];
#pragma unroll
    for (int a = 0; a < 2; ++a)
#pragma unroll
        for (int b = 0; b < 4; ++b)
#pragma unroll
            for (int c = 0; c < 3; ++c) prow[a][b][c] = 0.f;

    int  curI = -1;
    int  p = 0;
    bool wrote0 = false, wrote1 = false;

    for (int m = t0; m < t1; ++m) {
        int I, J;
        if (m < 128 - 2 * kp) { I = kp;      J = 2 * kp + m; }
        else                  { I = 63 - kp; J = m - 2; }
        const bool diag = ((J >> 1) == I);
        const int i0 = I * TI, j0 = J * TJ;

        if (I != curI) {
            const bool hadPrev = (curI >= 0);
            const int prevWhich = (curI == kp) ? 0 : 1;
            if (hadPrev) {
                // flush prow -> rowred (rows of the old i-tile)
#pragma unroll
                for (int rf = 0; rf < 2; ++rf)
#pragma unroll
                    for (int reg = 0; reg < 4; ++reg)
#pragma unroll
                        for (int ch = 0; ch < 3; ++ch) {
                            float v = prow[rf][reg][ch];
                            v += __shfl_xor(v, 1, 64);
                            v += __shfl_xor(v, 2, 64);
                            v += __shfl_xor(v, 4, 64);
                            v += __shfl_xor(v, 8, 64);
                            if ((lane & 15) == 0)
                                rowred[wc][wr * 32 + rf * 16 + ((lane >> 4) << 2) + reg][ch] = v;
                            prow[rf][reg][ch] = 0.f;
                        }
            }
            stage_A(XB, YB, i0, wid, lane, Alds);
            if (tid < 256) sqi[tid >> 7][tid & 127] = ((tid < 128) ? sqx : sqy)[i0 + (tid & 127)];
            __syncthreads();   // covers rowred write + A/sqi staging
            if (hadPrev && tid < 384) {
                int ch = tid >> 7, row = tid & 127;
                size_t slot = ((size_t)(kp * 16 + cch) * 2 + prevWhich);
                ROWS[(slot * 3 + ch) * 128 + row] = rowred[0][row][ch] + rowred[1][row][ch];
            }
            if (hadPrev) { if (prevWhich == 0) wrote0 = true; else wrote1 = true; }
            curI = I;
        }

        // ---- per-tile scalars: sqj from global (L2), sqi rows from LDS ----
        float sxj[2], syj[2];
#pragma unroll
        for (int cf = 0; cf < 2; ++cf) {
            int c = j0 + wc * 32 + cf * 16 + (lane & 15);
            sxj[cf] = sqx[c];
            syj[cf] = sqy[c];
        }
        f32x4 six[2], siy[2];
#pragma unroll
        for (int rf = 0; rf < 2; ++rf) {
            int rb = wr * 32 + rf * 16 + ((lane >> 4) << 2);
            six[rf] = *reinterpret_cast<const f32x4*>(&sqi[0][rb]);
            siy[rf] = *reinterpret_cast<const f32x4*>(&sqi[1][rb]);
        }

        // ---- MFMA: A from LDS (swizzled), B streamed from L2 ----
        f32x4 ax[2][2], ay[2][2];
#pragma unroll
        for (int rf = 0; rf < 2; ++rf)
#pragma unroll
            for (int cf = 0; cf < 2; ++cf) {
                ax[rf][cf] = (f32x4){0.f, 0.f, 0.f, 0.f};
                ay[rf][cf] = (f32x4){0.f, 0.f, 0.f, 0.f};
            }
#pragma unroll 2   // cap b-frag register liveness (full unroll would hoist 16 loads)
        for (int kk = 0; kk < 4; ++kk) {
            bf16x8 afx[2], afy[2], bfx[2], bfy[2];
#pragma unroll
            for (int rf = 0; rf < 2; ++rf) {
                int r  = wr * 32 + rf * 16 + (lane & 15);
                int sl = (kk * 4 + (lane >> 4)) ^ (r & 7);
                afx[rf] = *reinterpret_cast<const bf16x8*>(&Alds[0][r][sl * 8]);
                afy[rf] = *reinterpret_cast<const bf16x8*>(&Alds[1][r][sl * 8]);
            }
#pragma unroll
            for (int cf = 0; cf < 2; ++cf) {
                int col = j0 + wc * 32 + cf * 16 + (lane & 15);
                size_t off = (size_t)col * DD + kk * 32 + (lane >> 4) * 8;
                bfx[cf] = *reinterpret_cast<const bf16x8*>(XB + off);
                bfy[cf] = *reinterpret_cast<const bf16x8*>(YB + off);
            }
#pragma unroll
            for (int cf = 0; cf < 2; ++cf)
#pragma unroll
                for (int rf = 0; rf < 2; ++rf) {
                    ax[rf][cf] = __builtin_amdgcn_mfma_f32_16x16x32_bf16(afx[rf], bfx[cf], ax[rf][cf], 0, 0, 0);
                    ay[rf][cf] = __builtin_amdgcn_mfma_f32_16x16x32_bf16(afy[rf], bfy[cf], ay[rf][cf], 0, 0, 0);
                }
        }

        // ---- combine ----
        float pcol[2][3] = {{0.f,0.f,0.f},{0.f,0.f,0.f}};
        const int dj = j0 - i0;   // 0 or 64 for diag tiles
        if (same) { if (diag) do_combine<true , true >(ax, ay, six, siy, sxj, syj, cx2, cy2, m2cx, m2cy, rx, ry, dj, prow, pcol, wr, wc, lane);
                    else      do_combine<true , false>(ax, ay, six, siy, sxj, syj, cx2, cy2, m2cx, m2cy, rx, ry, dj, prow, pcol, wr, wc, lane); }
        else      { if (diag) do_combine<false, true >(ax, ay, six, siy, sxj, syj, cx2, cy2, m2cx, m2cy, rx, ry, dj, prow, pcol, wr, wc, lane);
                    else      do_combine<false, false>(ax, ay, six, siy, sxj, syj, cx2, cy2, m2cx, m2cy, rx, ry, dj, prow, pcol, wr, wc, lane); }

        // ---- col partials -> colred[p] ----
#pragma unroll
        for (int cf = 0; cf < 2; ++cf)
#pragma unroll
            for (int ch = 0; ch < 3; ++ch) {
                float v = pcol[cf][ch];
                v += __shfl_xor(v, 16, 64);
                v += __shfl_xor(v, 32, 64);
                if (lane < 16) colred[p][wr][wc * 32 + cf * 16 + lane][ch] = v;
            }

        __syncthreads();

        // ---- post-barrier: private COL slot store (no atomics; skip diag tiles) ----
        if (!diag && tid < 192) {
            int ch = tid >> 6, col = tid & 63;
            float v = colred[p][0][col][ch] + colred[p][1][col][ch]
                    + colred[p][2][col][ch] + colred[p][3][col][ch];
            int rank = I * (127 - I) + (J - 2 * I - 2);
            COL[((size_t)rank * 3 + ch) * 64 + col] = v;
        }
        p ^= 1;
    }

    // ---- final row flush ----
#pragma unroll
    for (int rf = 0; rf < 2; ++rf)
#pragma unroll
        for (int reg = 0; reg < 4; ++reg)
#pragma unroll
            for (int ch = 0; ch < 3; ++ch) {
                float v = prow[rf][reg][ch];
                v += __shfl_xor(v, 1, 64);
                v += __shfl_xor(v, 2, 64);
                v += __shfl_xor(v, 4, 64);
                v += __shfl_xor(v, 8, 64);
                if ((lane & 15) == 0)
                    rowred[wc][wr * 32 + rf * 16 + ((lane >> 4) << 2) + reg][ch] = v;
            }
    __syncthreads();
    {
        const int lastWhich = (curI == kp) ? 0 : 1;
        if (tid < 384) {
            int ch = tid >> 7, row = tid & 127;
            size_t slot = ((size_t)(kp * 16 + cch) * 2 + lastWhich);
            ROWS[(slot * 3 + ch) * 128 + row] = rowred[0][row][ch] + rowred[1][row][ch];
        }
        if (lastWhich == 0) wrote0 = true; else wrote1 = true;
    }
    // zero-fill untouched slot so lp can gather unconditionally
    if (!wrote0 && tid < 384) {
        int ch = tid >> 7, row = tid & 127;
        ROWS[(((size_t)(kp * 16 + cch) * 2 + 0) * 3 + ch) * 128 + row] = 0.f;
    }
    if (!wrote1 && tid < 384) {
        int ch = tid >> 7, row = tid & 127;
        ROWS[(((size_t)(kp * 16 + cch) * 2 + 1) * 3 + ch) * 128 + row] = 0.f;
    }
}

__global__ void lp_primary(const float* __restrict__ sjp, const float* __restrict__ sxp,
                           const float* __restrict__ syp,
                           const float* __restrict__ COL, const float* __restrict__ ROWS,
                           float* __restrict__ bsum) {
    int b = blockIdx.x;    // i-tile [0,64)
    int t = threadIdx.x;   // 128
    int r = b * 128 + t;
    float S0 = 0.f, S1 = 0.f, S2 = 0.f;
    int kp2 = (b < 32) ? b : 63 - b;
    int which = (b < 32) ? 0 : 1;
    for (int c = 0; c < 16; ++c) {
        size_t slot = ((size_t)(kp2 * 16 + c) * 2 + which) * 3;
        S0 += ROWS[(slot + 0) * 128 + t];
        S1 += ROWS[(slot + 1) * 128 + t];
        S2 += ROWS[(slot + 2) * 128 + t];
    }
    int J = r >> 6;            // 64-col tile containing this row-as-column
    int cnt = J >> 1;          // number of off-diag (I,J) tiles above
    for (int I = 0; I < cnt; ++I) {
        int rank = I * (127 - I) + (J - 2 * I - 2);
        size_t base = (size_t)rank * 192 + (r & 63);
        S0 += COL[base];
        S1 += COL[base + 64];
        S2 += COL[base + 128];
    }
    float sx = *sxp, sy = *syp, sj = *sjp;
    float logN = logf((float)NROW);
    float lpx = logf(S0) - (float)DD * logf(sx) - 0.5f * (float)DD * LOG_2PI - logN;
    float lpy = logf(S1) - (float)DD * logf(sy) - 0.5f * (float)DD * LOG_2PI - logN;
    float lpj = logf(S2) - 2.0f * (float)DD * logf(sj) - (float)DD * LOG_2PI - logN;
    float I_ = expf(lpj) * (lpj - lpx - lpy);
#pragma unroll
    for (int m = 1; m < 64; m <<= 1) I_ += __shfl_xor(I_, m, 64);
    __shared__ float w0s[2];
    if ((t & 63) == 0) w0s[t >> 6] = I_;
    __syncthreads();
    if (t == 0) bsum[b] = w0s[0] + w0s[1];
}

__global__ void final_reduce(const float* __restrict__ bsum, float* __restrict__ out) {
    int t = threadIdx.x;   // 64
    float v = bsum[t];
#pragma unroll
    for (int m = 1; m < 64; m <<= 1) v += __shfl_xor(v, m, 64);
    if (t == 0) out[0] = -v;
}

// ================= FALLBACK (round-2 proven; only if ws too small) =================
template <bool SAME>
__device__ __forceinline__ void fb_combine(const f32x4 (&ax)[4][2], const f32x4 (&ay)[4][2],
                                           const float (&sq)[4][TS],
                                           float (&rowred)[4][TS][3], float (&colred)[2][TS][3],
                                           int wr, int wc, int lane,
                                           float cx2, float cy2, float cj2) {
    float pcol[2][3] = {{0.f,0.f,0.f},{0.f,0.f,0.f}};
#pragma unroll
    for (int rf = 0; rf < 4; ++rf) {
        float prow[4][3] = {{0.f,0.f,0.f},{0.f,0.f,0.f},{0.f,0.f,0.f},{0.f,0.f,0.f}};
        float sxi[4], syi[4];
#pragma unroll
        for (int reg = 0; reg < 4; ++reg) {
            int row = wr*64 + rf*16 + ((lane>>4)<<2) + reg;
            sxi[reg] = sq[0][row]; syi[reg] = sq[1][row];
        }
#pragma unroll
        for (int cf = 0; cf < 2; ++cf) {
            int col = wc*32 + cf*16 + (lane & 15);
            float qx = sq[2][col], qy = sq[3][col];
#pragma unroll
            for (int reg = 0; reg < 4; ++reg) {
                float gx = ax[rf][cf][reg], gy = ay[rf][cf][reg];
                float d2x = fmaxf(fmaf(-2.f, gx, sxi[reg] + qx), 0.f);
                float d2y = fmaxf(fmaf(-2.f, gy, syi[reg] + qy), 0.f);
                float ex = fexp2(d2x * cx2);
                float ey = fexp2(d2y * cy2);
                float ej = SAME ? (ex * ey) : fexp2(fmaf(d2y, cj2, d2x * cj2));
                prow[reg][0] += ex; prow[reg][1] += ey; prow[reg][2] += ej;
                pcol[cf][0]  += ex; pcol[cf][1]  += ey; pcol[cf][2]  += ej;
            }
        }
#pragma unroll
        for (int reg = 0; reg < 4; ++reg)
#pragma unroll
            for (int ch = 0; ch < 3; ++ch) {
                float v = prow[reg][ch];
                v += __shfl_xor(v, 1, 64); v += __shfl_xor(v, 2, 64);
                v += __shfl_xor(v, 4, 64); v += __shfl_xor(v, 8, 64);
                if ((lane & 15) == 0)
                    rowred[wc][wr*64 + rf*16 + ((lane>>4)<<2) + reg][ch] = v;
            }
    }
#pragma unroll
    for (int cf = 0; cf < 2; ++cf)
#pragma unroll
        for (int ch = 0; ch < 3; ++ch) {
            float v = pcol[cf][ch];
            v += __shfl_xor(v, 16, 64); v += __shfl_xor(v, 32, 64);
            if (lane < 16) colred[wr][wc*32 + cf*16 + lane][ch] = v;
        }
}

__launch_bounds__(BLOCK)
__global__ void kde_fb(const float* __restrict__ X, const float* __restrict__ Y,
                       const float* __restrict__ sjp, const float* __restrict__ sxp,
                       const float* __restrict__ syp,
                       unsigned long long* __restrict__ acc,
                       const float* __restrict__ sqx, const float* __restrict__ sqy) {
    __shared__ unsigned short T[4][TS][DD];
    __shared__ float sq[4][TS];
    __shared__ float rowred[4][TS][3];
    __shared__ float colred[2][TS][3];

    const int tid  = threadIdx.x;
    const int lane = tid & 63;
    const int wid  = tid >> 6;
    const int wr   = wid >> 2;
    const int wc   = wid & 3;

    int b = (blockIdx.x & 7) * (NPAIR / 8) + (blockIdx.x >> 3);
    int ti = 0, rem = b;
    while (rem >= NT - ti) { rem -= NT - ti; ++ti; }
    int tj = ti + rem;
    const int i0 = ti * TS, j0 = tj * TS;

    const float sxv = *sxp, syv = *syp, sjv = *sjp;
    const float cx2 = -0.5f * L2E / (sxv * sxv);
    const float cy2 = -0.5f * L2E / (syv * syv);
    const float cj2 = -0.5f * L2E / (sjv * sjv);
    const bool samesig = (cx2 == cy2) && (cy2 == cj2);

    for (int c = tid; c < 8192; c += BLOCK) {
        int t = c >> 11, row = (c >> 4) & 127, col8 = c & 15;
        const float* base =
            (t == 0) ? X + (size_t)i0 * DD : (t == 1) ? Y + (size_t)i0 * DD :
            (t == 2) ? X + (size_t)j0 * DD : Y + (size_t)j0 * DD;
        const float4* s4 = reinterpret_cast<const float4*>(base + row * DD + col8 * 8);
        float4 a = s4[0], bb = s4[1];
        unsigned int w0 = (unsigned int)f2bf(a.x)  | ((unsigned int)f2bf(a.y)  << 16);
        unsigned int w1 = (unsigned int)f2bf(a.z)  | ((unsigned int)f2bf(a.w)  << 16);
        unsigned int w2 = (unsigned int)f2bf(bb.x) | ((unsigned int)f2bf(bb.y) << 16);
        unsigned int w3 = (unsigned int)f2bf(bb.z) | ((unsigned int)f2bf(bb.w) << 16);
        uint4 pk = make_uint4(w0, w1, w2, w3);
        int sl = (col8 ^ (row & 7)) << 3;
        *reinterpret_cast<uint4*>(&T[t][row][sl]) = pk;
    }
    {
        int t = tid >> 7, r = tid & 127;
        const float* s = (t == 0) ? sqx + i0 : (t == 1) ? sqy + i0
                       : (t == 2) ? sqx + j0 : sqy + j0;
        sq[t][r] = s[r];
    }
    __syncthreads();

    f32x4 ax[4][2], ay[4][2];
#pragma unroll
    for (int rf = 0; rf < 4; ++rf)
#pragma unroll
        for (int cf = 0; cf < 2; ++cf) {
            ax[rf][cf] = (f32x4){0.f,0.f,0.f,0.f};
            ay[rf][cf] = (f32x4){0.f,0.f,0.f,0.f};
        }
#pragma unroll
    for (int kk = 0; kk < 4; ++kk) {
        const int k0 = kk * 4 + (lane >> 4);
        bf16x8 afx[4], afy[4], bfx[2], bfy[2];
#pragma unroll
        for (int rf = 0; rf < 4; ++rf) {
            int r  = wr * 64 + rf * 16 + (lane & 15);
            int sl = (k0 ^ (r & 7)) << 3;
            afx[rf] = *reinterpret_cast<const bf16x8*>(&T[0][r][sl]);
            afy[rf] = *reinterpret_cast<const bf16x8*>(&T[1][r][sl]);
        }
#pragma unroll
        for (int cf = 0; cf < 2; ++cf) {
            int r  = wc * 32 + cf * 16 + (lane & 15);
            int sl = (k0 ^ (r & 7)) << 3;
            bfx[cf] = *reinterpret_cast<const bf16x8*>(&T[2][r][sl]);
            bfy[cf] = *reinterpret_cast<const bf16x8*>(&T[3][r][sl]);
        }
#pragma unroll
        for (int rf = 0; rf < 4; ++rf)
#pragma unroll
            for (int cf = 0; cf < 2; ++cf) {
                ax[rf][cf] = __builtin_amdgcn_mfma_f32_16x16x32_bf16(afx[rf], bfx[cf], ax[rf][cf], 0, 0, 0);
                ay[rf][cf] = __builtin_amdgcn_mfma_f32_16x16x32_bf16(afy[rf], bfy[cf], ay[rf][cf], 0, 0, 0);
            }
    }

    if (samesig) fb_combine<true >(ax, ay, sq, rowred, colred, wr, wc, lane, cx2, cy2, cj2);
    else         fb_combine<false>(ax, ay, sq, rowred, colred, wr, wc, lane, cx2, cy2, cj2);
    __syncthreads();

    if (tid < TS) {
        int r = tid;
#pragma unroll
        for (int ch = 0; ch < 3; ++ch) {
            float v = rowred[0][r][ch] + rowred[1][r][ch] + rowred[2][r][ch] + rowred[3][r][ch];
            atomicAdd(&acc[(size_t)(i0 + r) * 3 + ch],
                      (unsigned long long)(long long)((double)v * FP_SCALE));
        }
    } else if (tid < 2 * TS && ti != tj) {
        int r = tid - TS;
#pragma unroll
        for (int ch = 0; ch < 3; ++ch) {
            float v = colred[0][r][ch] + colred[1][r][ch];
            atomicAdd(&acc[(size_t)(j0 + r) * 3 + ch],
                      (unsigned long long)(long long)((double)v * FP_SCALE));
        }
    }
}

__global__ void lp_fb(const float* __restrict__ sjp, const float* __restrict__ sxp,
                      const float* __restrict__ syp,
                      const unsigned long long* __restrict__ acc,
                      float* __restrict__ bsum) {
    int b = blockIdx.x, t = threadIdx.x;
    size_t row = (size_t)b * 128 + t;
    const double INV = 1.0 / FP_SCALE;
    float S0 = (float)((double)acc[row * 3 + 0] * INV);
    float S1 = (float)((double)acc[row * 3 + 1] * INV);
    float S2 = (float)((double)acc[row * 3 + 2] * INV);
    float sx = *sxp, sy = *syp, sj = *sjp;
    float logN = logf((float)NROW);
    float lpx = logf(S0) - (float)DD * logf(sx) - 0.5f * (float)DD * LOG_2PI - logN;
    float lpy = logf(S1) - (float)DD * logf(sy) - 0.5f * (float)DD * LOG_2PI - logN;
    float lpj = logf(S2) - 2.0f * (float)DD * logf(sj) - (float)DD * LOG_2PI - logN;
    float I = expf(lpj) * (lpj - lpx - lpy);
#pragma unroll
    for (int m = 1; m < 64; m <<= 1) I += __shfl_xor(I, m, 64);
    __shared__ float w0[2];
    if ((t & 63) == 0) w0[t >> 6] = I;
    __syncthreads();
    if (t == 0) bsum[b] = w0[0] + w0[1];
}

extern "C" void kernel_launch(void* const* d_in, const int* in_sizes, int n_in,
                              void* d_out, int out_size, void* d_ws, size_t ws_size,
                              hipStream_t stream) {
    (void)in_sizes; (void)n_in; (void)out_size;
    const float* X  = (const float*)d_in[0];
    const float* Y  = (const float*)d_in[1];
    const float* sj = (const float*)d_in[2];
    const float* sx = (const float*)d_in[3];
    const float* sy = (const float*)d_in[4];
    float* out = (float*)d_out;
    char*  w   = (char*)d_ws;

    float* SQX  = (float*)(w + SQX_B);
    float* SQY  = (float*)(w + SQY_B);
    float* BSUM = (float*)(w + BSUM_B);
    float* COLS = (float*)(w + COL_B);
    float* ROWS = (float*)(w + ROW_B);
    unsigned short* XB = (unsigned short*)(w + XB_B);
    unsigned short* YB = (unsigned short*)(w + YB_B);

    if (ws_size >= (size_t)PRIMARY_NEED) {
        sq_kernel<true ><<<dim3(2048), dim3(256), 0, stream>>>(X, Y, SQX, SQY, XB, YB);
        kde_primary<<<dim3(NBLK), dim3(BLOCK), 0, stream>>>(XB, YB, sj, sx, sy, SQX, SQY, COLS, ROWS);
        lp_primary<<<dim3(64), dim3(128), 0, stream>>>(sj, sx, sy, COLS, ROWS, BSUM);
    } else {
        unsigned long long* ACC = (unsigned long long*)(w + ACC_B);
        hipMemsetAsync(w + ACC_B, 0, NROW * 3 * sizeof(unsigned long long), stream);
        sq_kernel<false><<<dim3(2048), dim3(256), 0, stream>>>(X, Y, SQX, SQY, XB, YB);
        kde_fb<<<dim3(NPAIR), dim3(BLOCK), 0, stream>>>(X, Y, sj, sx, sy, ACC, SQX, SQY);
        lp_fb<<<dim3(64), dim3(128), 0, stream>>>(sj, sx, sy, ACC, BSUM);
    }
    final_reduce<<<dim3(1), dim3(64), 0, stream>>>(BSUM, out);
}

// Round 8
// 115.883 us; speedup vs baseline: 1.6051x; 1.1714x over previous
//
#include <hip/hip_runtime.h>
#include <hip/hip_bf16.h>
#include <math.h>

#define NROW 8192
#define DD   128

// v8 primary geometry
#define TI   64
#define TJ   64
#define BLK  256
#define NBLK 1024
#define NRANK 8128        // off-diag tiles on 128-grid: 128*127/2

// fallback geometry (round-2 proven)
#define NT   64
#define TS   128
#define NPAIR 2080
#define FBLOCK 512

#define LOG_2PI 1.8378770664093453f
#define L2E     1.4426950408889634f
#define FP_SCALE 1099511627776.0   // 2^40 (fallback only)

typedef __attribute__((ext_vector_type(8))) short bf16x8;
typedef __attribute__((ext_vector_type(4))) float f32x4;

// ---- ws byte layout ----
#define SQX_B 0
#define SQY_B 32768
#define BSUM_B 65536
#define COL_B 65792                               // 8128*3*64*4 = 6,242,304
#define ROW_B (COL_B + NRANK*3*64*4)              // 2048*3*64*4 = 1,572,864
#define XB_B  (ROW_B + 2048*3*64*4)
#define YB_B  (XB_B + NROW*DD*2)
#define PRIMARY_NEED (YB_B + NROW*DD*2)           // 12,075,264 B
#define ACC_B COL_B                               // fallback overlays

__device__ __forceinline__ unsigned short f2bf(float f) {
    unsigned int x = __float_as_uint(f);
    unsigned int r = (x + 0x7fffu + ((x >> 16) & 1u)) >> 16;  // RNE
    return (unsigned short)r;
}
__device__ __forceinline__ float fexp2(float x) { return __builtin_amdgcn_exp2f(x); }

// ---------------- row squared norms (+ optional bf16 precopy) ----------------
template <bool PRE>
__global__ void sq_kernel(const float* __restrict__ X, const float* __restrict__ Y,
                          float* __restrict__ sqx, float* __restrict__ sqy,
                          unsigned short* __restrict__ XB, unsigned short* __restrict__ YB) {
    int tid  = threadIdx.x;
    int rowg = blockIdx.x * 8 + (tid >> 5);
    int lane = tid & 31;
    bool isX = rowg < NROW;
    const float* src = isX ? (X + (size_t)rowg * DD) : (Y + (size_t)(rowg - NROW) * DD);
    float4 v = reinterpret_cast<const float4*>(src)[lane];
    if (PRE) {
        unsigned int w0 = (unsigned int)f2bf(v.x) | ((unsigned int)f2bf(v.y) << 16);
        unsigned int w1 = (unsigned int)f2bf(v.z) | ((unsigned int)f2bf(v.w) << 16);
        unsigned short* dst = (isX ? XB + (size_t)rowg * DD
                                   : YB + (size_t)(rowg - NROW) * DD) + lane * 4;
        uint2 pk; pk.x = w0; pk.y = w1;
        *reinterpret_cast<uint2*>(dst) = pk;
    }
    float s = v.x * v.x + v.y * v.y + v.z * v.z + v.w * v.w;
#pragma unroll
    for (int m = 16; m; m >>= 1) s += __shfl_xor(s, m, 64);
    if (lane == 0) { if (isX) sqx[rowg] = s; else sqy[rowg - NROW] = s; }
}

// ================= PRIMARY v8: 4 waves, barrier-free tile loop =================
// Block = (row-pair p, chunk). Tiles (I,J) on the 64-row grid, J >= I.
// Wave wq owns cols [wq*16, wq*16+16) of each 64-col j-tile, ALL 64 rows (rf=4).
// -> col sums wave-local (private COL slot store, no barrier);
//    row sums cross-wave, flushed via LDS only at I-switch (<=2 per block).

template <bool SAME, bool DIAG>
__device__ __forceinline__ void combine_v8(const f32x4 (&ax)[4], const f32x4 (&ay)[4],
                                           const float* __restrict__ sqi0,
                                           const float* __restrict__ sqi1,
                                           float bxp, float byp,
                                           float cx2, float cy2, float m2cx, float m2cy,
                                           float rx, float ry,
                                           float (&prow)[4][4][3], float (&pcol)[3],
                                           int lane, int wq) {
    const int coll = wq * 16 + (lane & 15);
#pragma unroll
    for (int rf = 0; rf < 4; ++rf) {
        const int rb = rf * 16 + ((lane >> 4) << 2);
        f32x4 sixv = *reinterpret_cast<const f32x4*>(&sqi0[rb]);
        f32x4 siyv = *reinterpret_cast<const f32x4*>(&sqi1[rb]);
#pragma unroll
        for (int reg = 0; reg < 4; ++reg) {
            float tx = fmaf(ax[rf][reg], m2cx, fmaf(cx2, sixv[reg], bxp));
            float ty = fmaf(ay[rf][reg], m2cy, fmaf(cy2, siyv[reg], byp));
            float ex = fexp2(tx);
            float ey = fexp2(ty);
            float ej = SAME ? (ex * ey) : fexp2(fmaf(tx, rx, ty * ry));
            if (DIAG) {
                bool dg = (rb + reg) == coll;
                ex = dg ? 1.f : ex;  ey = dg ? 1.f : ey;  ej = dg ? 1.f : ej;
            }
            prow[rf][reg][0] += ex; prow[rf][reg][1] += ey; prow[rf][reg][2] += ej;
            pcol[0] += ex;          pcol[1] += ey;          pcol[2] += ej;
        }
    }
}

__launch_bounds__(BLK, 1)   // min 1 wave/EU: lift the 128-VGPR cap (r4-6 spill saga)
__global__ void kde_primary(const unsigned short* __restrict__ XB,
                            const unsigned short* __restrict__ YB,
                            const float* __restrict__ sjp, const float* __restrict__ sxp,
                            const float* __restrict__ syp,
                            const float* __restrict__ sqx, const float* __restrict__ sqy,
                            float* __restrict__ COL, float* __restrict__ ROWS) {
    __shared__ unsigned short A[2][TI][DD];    // 32 KB, XOR-swizzled 16B slots
    __shared__ float sqi[2][TI];               // 0.5 KB
    __shared__ float rowred[4][TI][3];         // 3 KB

    const int tid  = threadIdx.x;
    const int lane = tid & 63;
    const int wq   = tid >> 6;     // 0..3 : 16-col slice owner

    const int bid = blockIdx.x;
    const int p   = (bid & 7) * 8 + ((bid >> 3) & 7);   // [0,64) row-pair; bid&7 = XCD
    const int cch = bid >> 6;                           // [0,16)
    const int t0  = (129 * cch) >> 4;
    const int t1  = (129 * (cch + 1)) >> 4;

    const float sxv = *sxp, syv = *syp, sjv = *sjp;
    const float cx2 = -0.5f * L2E / (sxv * sxv);
    const float cy2 = -0.5f * L2E / (syv * syv);
    const float cj2 = -0.5f * L2E / (sjv * sjv);
    const bool  same = (cx2 == cy2) && (cy2 == cj2);
    const float m2cx = -2.f * cx2, m2cy = -2.f * cy2;
    const float rx = cj2 / cx2, ry = cj2 / cy2;

    float prow[4][4][3];
#pragma unroll
    for (int a = 0; a < 4; ++a)
#pragma unroll
        for (int b = 0; b < 4; ++b)
#pragma unroll
            for (int c = 0; c < 3; ++c) prow[a][b][c] = 0.f;

    int  curI = -1;
    bool wrote0 = false, wrote1 = false;

    for (int m = t0; m < t1; ++m) {
        int I, J;
        if (m < 128 - p) { I = p;       J = p + m; }
        else             { I = 127 - p; J = m - 1; }
        const bool diag = (I == J);
        const int j0 = J * TJ;

        if (I != curI) {
            const bool hadPrev = (curI >= 0);
            const int prevWhich = (curI == p) ? 0 : 1;
            __syncthreads();   // waves done reading old A / rowred
            if (hadPrev) {
                // reduce prow over the wave's 16 cols, deposit per-wave row sums
#pragma unroll
                for (int rf = 0; rf < 4; ++rf)
#pragma unroll
                    for (int reg = 0; reg < 4; ++reg)
#pragma unroll
                        for (int ch = 0; ch < 3; ++ch) {
                            float v = prow[rf][reg][ch];
                            v += __shfl_xor(v, 1, 64);
                            v += __shfl_xor(v, 2, 64);
                            v += __shfl_xor(v, 4, 64);
                            v += __shfl_xor(v, 8, 64);
                            if ((lane & 15) == 0)
                                rowred[wq][rf * 16 + ((lane >> 4) << 2) + reg][ch] = v;
                            prow[rf][reg][ch] = 0.f;
                        }
            }
            // stage new A-tile (does not touch rowred)
            {
                int mat   = wq >> 1;
                int rband = (wq & 1) * 32;
                const unsigned short* gb = (mat ? YB : XB) + (size_t)(I * TI) * DD;
#pragma unroll
                for (int i = 0; i < 8; ++i) {
                    int row = rband + i * 4 + (lane >> 4);
                    uint4 v = *reinterpret_cast<const uint4*>(gb + (size_t)row * DD + (lane & 15) * 8);
                    int sl = (lane & 15) ^ (row & 7);
                    *reinterpret_cast<uint4*>(&A[mat][row][sl * 8]) = v;
                }
            }
            if (tid < 128) sqi[tid >> 6][tid & 63] = ((tid < 64) ? sqx : sqy)[I * TI + (tid & 63)];
            __syncthreads();
            if (hadPrev && tid < 192) {
                int ch = tid >> 6, row = tid & 63;
                size_t slot = ((size_t)(p * 16 + cch) * 2 + prevWhich);
                ROWS[(slot * 3 + ch) * 64 + row] = rowred[0][row][ch] + rowred[1][row][ch]
                                                 + rowred[2][row][ch] + rowred[3][row][ch];
            }
            if (hadPrev) { if (prevWhich == 0) wrote0 = true; else wrote1 = true; }
            curI = I;
        }

        // per-tile col constants (L2)
        const int colg = j0 + wq * 16 + (lane & 15);
        const float bxp = cx2 * sqx[colg];
        const float byp = cy2 * sqy[colg];

        // ---- MFMA: A from LDS, B streamed from L2 ----
        f32x4 ax[4], ay[4];
#pragma unroll
        for (int rf = 0; rf < 4; ++rf) {
            ax[rf] = (f32x4){0.f, 0.f, 0.f, 0.f};
            ay[rf] = (f32x4){0.f, 0.f, 0.f, 0.f};
        }
#pragma unroll 2
        for (int kk = 0; kk < 4; ++kk) {
            bf16x8 bfx, bfy, afx[4], afy[4];
            {
                size_t off = (size_t)colg * DD + kk * 32 + (lane >> 4) * 8;
                bfx = *reinterpret_cast<const bf16x8*>(XB + off);
                bfy = *reinterpret_cast<const bf16x8*>(YB + off);
            }
#pragma unroll
            for (int rf = 0; rf < 4; ++rf) {
                int r  = rf * 16 + (lane & 15);
                int sl = (kk * 4 + (lane >> 4)) ^ (r & 7);
                afx[rf] = *reinterpret_cast<const bf16x8*>(&A[0][r][sl * 8]);
                afy[rf] = *reinterpret_cast<const bf16x8*>(&A[1][r][sl * 8]);
            }
#pragma unroll
            for (int rf = 0; rf < 4; ++rf) {
                ax[rf] = __builtin_amdgcn_mfma_f32_16x16x32_bf16(afx[rf], bfx, ax[rf], 0, 0, 0);
                ay[rf] = __builtin_amdgcn_mfma_f32_16x16x32_bf16(afy[rf], bfy, ay[rf], 0, 0, 0);
            }
        }

        // ---- combine (no barrier) ----
        float pcol[3] = {0.f, 0.f, 0.f};
        if (same) { if (diag) combine_v8<true , true >(ax, ay, &sqi[0][0], &sqi[1][0], bxp, byp, cx2, cy2, m2cx, m2cy, rx, ry, prow, pcol, lane, wq);
                    else      combine_v8<true , false>(ax, ay, &sqi[0][0], &sqi[1][0], bxp, byp, cx2, cy2, m2cx, m2cy, rx, ry, prow, pcol, lane, wq); }
        else      { if (diag) combine_v8<false, true >(ax, ay, &sqi[0][0], &sqi[1][0], bxp, byp, cx2, cy2, m2cx, m2cy, rx, ry, prow, pcol, lane, wq);
                    else      combine_v8<false, false>(ax, ay, &sqi[0][0], &sqi[1][0], bxp, byp, cx2, cy2, m2cx, m2cy, rx, ry, prow, pcol, lane, wq); }

        // ---- wave-local col flush -> private COL slot (no barrier, no atomics) ----
        if (!diag) {
            int rank = I * 127 - (I * (I - 1)) / 2 + (J - I - 1);
#pragma unroll
            for (int ch = 0; ch < 3; ++ch) {
                float v = pcol[ch];
                v += __shfl_xor(v, 16, 64);
                v += __shfl_xor(v, 32, 64);
                if (lane < 16)
                    COL[((size_t)rank * 3 + ch) * 64 + wq * 16 + lane] = v;
            }
        }
    }

    // ---- final row flush ----
    __syncthreads();
#pragma unroll
    for (int rf = 0; rf < 4; ++rf)
#pragma unroll
        for (int reg = 0; reg < 4; ++reg)
#pragma unroll
            for (int ch = 0; ch < 3; ++ch) {
                float v = prow[rf][reg][ch];
                v += __shfl_xor(v, 1, 64);
                v += __shfl_xor(v, 2, 64);
                v += __shfl_xor(v, 4, 64);
                v += __shfl_xor(v, 8, 64);
                if ((lane & 15) == 0)
                    rowred[wq][rf * 16 + ((lane >> 4) << 2) + reg][ch] = v;
            }
    __syncthreads();
    {
        const int lastWhich = (curI == p) ? 0 : 1;
        if (tid < 192) {
            int ch = tid >> 6, row = tid & 63;
            size_t slot = ((size_t)(p * 16 + cch) * 2 + lastWhich);
            ROWS[(slot * 3 + ch) * 64 + row] = rowred[0][row][ch] + rowred[1][row][ch]
                                             + rowred[2][row][ch] + rowred[3][row][ch];
        }
        if (lastWhich == 0) wrote0 = true; else wrote1 = true;
    }
    if (!wrote0 && tid < 192) {
        int ch = tid >> 6, row = tid & 63;
        ROWS[(((size_t)(p * 16 + cch) * 2 + 0) * 3 + ch) * 64 + row] = 0.f;
    }
    if (!wrote1 && tid < 192) {
        int ch = tid >> 6, row = tid & 63;
        ROWS[(((size_t)(p * 16 + cch) * 2 + 1) * 3 + ch) * 64 + row] = 0.f;
    }
}

__global__ void lp_primary(const float* __restrict__ sjp, const float* __restrict__ sxp,
                           const float* __restrict__ syp,
                           const float* __restrict__ COL, const float* __restrict__ ROWS,
                           float* __restrict__ bsum) {
    int b = blockIdx.x;    // [0,64): 128 rows each
    int t = threadIdx.x;   // 128
    int r = b * 128 + t;
    int Ib = r >> 6;       // 64-row band [0,128)
    int c  = r & 63;
    float S0 = 0.f, S1 = 0.f, S2 = 0.f;
    {
        int p = (Ib < 64) ? Ib : 127 - Ib;
        int which = (Ib < 64) ? 0 : 1;
        for (int ch4 = 0; ch4 < 16; ++ch4) {
            size_t slot = ((size_t)(p * 16 + ch4) * 2 + which) * 3;
            S0 += ROWS[(slot + 0) * 64 + c];
            S1 += ROWS[(slot + 1) * 64 + c];
            S2 += ROWS[(slot + 2) * 64 + c];
        }
    }
    for (int I = 0; I < Ib; ++I) {
        size_t rank = (size_t)(I * 127 - (I * (I - 1)) / 2 + (Ib - I - 1));
        S0 += COL[(rank * 3 + 0) * 64 + c];
        S1 += COL[(rank * 3 + 1) * 64 + c];
        S2 += COL[(rank * 3 + 2) * 64 + c];
    }
    float sx = *sxp, sy = *syp, sj = *sjp;
    float logN = logf((float)NROW);
    float lpx = logf(S0) - (float)DD * logf(sx) - 0.5f * (float)DD * LOG_2PI - logN;
    float lpy = logf(S1) - (float)DD * logf(sy) - 0.5f * (float)DD * LOG_2PI - logN;
    float lpj = logf(S2) - 2.0f * (float)DD * logf(sj) - (float)DD * LOG_2PI - logN;
    float I_ = expf(lpj) * (lpj - lpx - lpy);
#pragma unroll
    for (int m = 1; m < 64; m <<= 1) I_ += __shfl_xor(I_, m, 64);
    __shared__ float w0s[2];
    if ((t & 63) == 0) w0s[t >> 6] = I_;
    __syncthreads();
    if (t == 0) bsum[b] = w0s[0] + w0s[1];
}

__global__ void final_reduce(const float* __restrict__ bsum, float* __restrict__ out) {
    int t = threadIdx.x;   // 64
    float v = bsum[t];
#pragma unroll
    for (int m = 1; m < 64; m <<= 1) v += __shfl_xor(v, m, 64);
    if (t == 0) out[0] = -v;
}

// ================= FALLBACK (round-2 proven; only if ws too small) =================
template <bool SAME>
__device__ __forceinline__ void fb_combine(const f32x4 (&ax)[4][2], const f32x4 (&ay)[4][2],
                                           const float (&sq)[4][TS],
                                           float (&rowred)[4][TS][3], float (&colred)[2][TS][3],
                                           int wr, int wc, int lane,
                                           float cx2, float cy2, float cj2) {
    float pcol[2][3] = {{0.f,0.f,0.f},{0.f,0.f,0.f}};
#pragma unroll
    for (int rf = 0; rf < 4; ++rf) {
        float prow[4][3] = {{0.f,0.f,0.f},{0.f,0.f,0.f},{0.f,0.f,0.f},{0.f,0.f,0.f}};
        float sxi[4], syi[4];
#pragma unroll
        for (int reg = 0; reg < 4; ++reg) {
            int row = wr*64 + rf*16 + ((lane>>4)<<2) + reg;
            sxi[reg] = sq[0][row]; syi[reg] = sq[1][row];
        }
#pragma unroll
        for (int cf = 0; cf < 2; ++cf) {
            int col = wc*32 + cf*16 + (lane & 15);
            float qx = sq[2][col], qy = sq[3][col];
#pragma unroll
            for (int reg = 0; reg < 4; ++reg) {
                float gx = ax[rf][cf][reg], gy = ay[rf][cf][reg];
                float d2x = fmaxf(fmaf(-2.f, gx, sxi[reg] + qx), 0.f);
                float d2y = fmaxf(fmaf(-2.f, gy, syi[reg] + qy), 0.f);
                float ex = fexp2(d2x * cx2);
                float ey = fexp2(d2y * cy2);
                float ej = SAME ? (ex * ey) : fexp2(fmaf(d2y, cj2, d2x * cj2));
                prow[reg][0] += ex; prow[reg][1] += ey; prow[reg][2] += ej;
                pcol[cf][0]  += ex; pcol[cf][1]  += ey; pcol[cf][2]  += ej;
            }
        }
#pragma unroll
        for (int reg = 0; reg < 4; ++reg)
#pragma unroll
            for (int ch = 0; ch < 3; ++ch) {
                float v = prow[reg][ch];
                v += __shfl_xor(v, 1, 64); v += __shfl_xor(v, 2, 64);
                v += __shfl_xor(v, 4, 64); v += __shfl_xor(v, 8, 64);
                if ((lane & 15) == 0)
                    rowred[wc][wr*64 + rf*16 + ((lane>>4)<<2) + reg][ch] = v;
            }
    }
#pragma unroll
    for (int cf = 0; cf < 2; ++cf)
#pragma unroll
        for (int ch = 0; ch < 3; ++ch) {
            float v = pcol[cf][ch];
            v += __shfl_xor(v, 16, 64); v += __shfl_xor(v, 32, 64);
            if (lane < 16) colred[wr][wc*32 + cf*16 + lane][ch] = v;
        }
}

__launch_bounds__(FBLOCK)
__global__ void kde_fb(const float* __restrict__ X, const float* __restrict__ Y,
                       const float* __restrict__ sjp, const float* __restrict__ sxp,
                       const float* __restrict__ syp,
                       unsigned long long* __restrict__ acc,
                       const float* __restrict__ sqx, const float* __restrict__ sqy) {
    __shared__ unsigned short T[4][TS][DD];
    __shared__ float sq[4][TS];
    __shared__ float rowred[4][TS][3];
    __shared__ float colred[2][TS][3];

    const int tid  = threadIdx.x;
    const int lane = tid & 63;
    const int wid  = tid >> 6;
    const int wr   = wid >> 2;
    const int wc   = wid & 3;

    int b = (blockIdx.x & 7) * (NPAIR / 8) + (blockIdx.x >> 3);
    int ti = 0, rem = b;
    while (rem >= NT - ti) { rem -= NT - ti; ++ti; }
    int tj = ti + rem;
    const int i0 = ti * TS, j0 = tj * TS;

    const float sxv = *sxp, syv = *syp, sjv = *sjp;
    const float cx2 = -0.5f * L2E / (sxv * sxv);
    const float cy2 = -0.5f * L2E / (syv * syv);
    const float cj2 = -0.5f * L2E / (sjv * sjv);
    const bool samesig = (cx2 == cy2) && (cy2 == cj2);

    for (int c = tid; c < 8192; c += FBLOCK) {
        int t = c >> 11, row = (c >> 4) & 127, col8 = c & 15;
        const float* base =
            (t == 0) ? X + (size_t)i0 * DD : (t == 1) ? Y + (size_t)i0 * DD :
            (t == 2) ? X + (size_t)j0 * DD : Y + (size_t)j0 * DD;
        const float4* s4 = reinterpret_cast<const float4*>(base + row * DD + col8 * 8);
        float4 a = s4[0], bb = s4[1];
        unsigned int w0 = (unsigned int)f2bf(a.x)  | ((unsigned int)f2bf(a.y)  << 16);
        unsigned int w1 = (unsigned int)f2bf(a.z)  | ((unsigned int)f2bf(a.w)  << 16);
        unsigned int w2 = (unsigned int)f2bf(bb.x) | ((unsigned int)f2bf(bb.y) << 16);
        unsigned int w3 = (unsigned int)f2bf(bb.z) | ((unsigned int)f2bf(bb.w) << 16);
        uint4 pk = make_uint4(w0, w1, w2, w3);
        int sl = (col8 ^ (row & 7)) << 3;
        *reinterpret_cast<uint4*>(&T[t][row][sl]) = pk;
    }
    {
        int t = tid >> 7, r = tid & 127;
        const float* s = (t == 0) ? sqx + i0 : (t == 1) ? sqy + i0
                       : (t == 2) ? sqx + j0 : sqy + j0;
        sq[t][r] = s[r];
    }
    __syncthreads();

    f32x4 ax[4][2], ay[4][2];
#pragma unroll
    for (int rf = 0; rf < 4; ++rf)
#pragma unroll
        for (int cf = 0; cf < 2; ++cf) {
            ax[rf][cf] = (f32x4){0.f,0.f,0.f,0.f};
            ay[rf][cf] = (f32x4){0.f,0.f,0.f,0.f};
        }
#pragma unroll
    for (int kk = 0; kk < 4; ++kk) {
        const int k0 = kk * 4 + (lane >> 4);
        bf16x8 afx[4], afy[4], bfx[2], bfy[2];
#pragma unroll
        for (int rf = 0; rf < 4; ++rf) {
            int r  = wr * 64 + rf * 16 + (lane & 15);
            int sl = (k0 ^ (r & 7)) << 3;
            afx[rf] = *reinterpret_cast<const bf16x8*>(&T[0][r][sl]);
            afy[rf] = *reinterpret_cast<const bf16x8*>(&T[1][r][sl]);
        }
#pragma unroll
        for (int cf = 0; cf < 2; ++cf) {
            int r  = wc * 32 + cf * 16 + (lane & 15);
            int sl = (k0 ^ (r & 7)) << 3;
            bfx[cf] = *reinterpret_cast<const bf16x8*>(&T[2][r][sl]);
            bfy[cf] = *reinterpret_cast<const bf16x8*>(&T[3][r][sl]);
        }
#pragma unroll
        for (int rf = 0; rf < 4; ++rf)
#pragma unroll
            for (int cf = 0; cf < 2; ++cf) {
                ax[rf][cf] = __builtin_amdgcn_mfma_f32_16x16x32_bf16(afx[rf], bfx[cf], ax[rf][cf], 0, 0, 0);
                ay[rf][cf] = __builtin_amdgcn_mfma_f32_16x16x32_bf16(afy[rf], bfy[cf], ay[rf][cf], 0, 0, 0);
            }
    }

    if (samesig) fb_combine<true >(ax, ay, sq, rowred, colred, wr, wc, lane, cx2, cy2, cj2);
    else         fb_combine<false>(ax, ay, sq, rowred, colred, wr, wc, lane, cx2, cy2, cj2);
    __syncthreads();

    if (tid < TS) {
        int r = tid;
#pragma unroll
        for (int ch = 0; ch < 3; ++ch) {
            float v = rowred[0][r][ch] + rowred[1][r][ch] + rowred[2][r][ch] + rowred[3][r][ch];
            atomicAdd(&acc[(size_t)(i0 + r) * 3 + ch],
                      (unsigned long long)(long long)((double)v * FP_SCALE));
        }
    } else if (tid < 2 * TS && ti != tj) {
        int r = tid - TS;
#pragma unroll
        for (int ch = 0; ch < 3; ++ch) {
            float v = colred[0][r][ch] + colred[1][r][ch];
            atomicAdd(&acc[(size_t)(j0 + r) * 3 + ch],
                      (unsigned long long)(long long)((double)v * FP_SCALE));
        }
    }
}

__global__ void lp_fb(const float* __restrict__ sjp, const float* __restrict__ sxp,
                      const float* __restrict__ syp,
                      const unsigned long long* __restrict__ acc,
                      float* __restrict__ bsum) {
    int b = blockIdx.x, t = threadIdx.x;
    size_t row = (size_t)b * 128 + t;
    const double INV = 1.0 / FP_SCALE;
    float S0 = (float)((double)acc[row * 3 + 0] * INV);
    float S1 = (float)((double)acc[row * 3 + 1] * INV);
    float S2 = (float)((double)acc[row * 3 + 2] * INV);
    float sx = *sxp, sy = *syp, sj = *sjp;
    float logN = logf((float)NROW);
    float lpx = logf(S0) - (float)DD * logf(sx) - 0.5f * (float)DD * LOG_2PI - logN;
    float lpy = logf(S1) - (float)DD * logf(sy) - 0.5f * (float)DD * LOG_2PI - logN;
    float lpj = logf(S2) - 2.0f * (float)DD * logf(sj) - (float)DD * LOG_2PI - logN;
    float I = expf(lpj) * (lpj - lpx - lpy);
#pragma unroll
    for (int m = 1; m < 64; m <<= 1) I += __shfl_xor(I, m, 64);
    __shared__ float w0[2];
    if ((t & 63) == 0) w0[t >> 6] = I;
    __syncthreads();
    if (t == 0) bsum[b] = w0[0] + w0[1];
}

extern "C" void kernel_launch(void* const* d_in, const int* in_sizes, int n_in,
                              void* d_out, int out_size, void* d_ws, size_t ws_size,
                              hipStream_t stream) {
    (void)in_sizes; (void)n_in; (void)out_size;
    const float* X  = (const float*)d_in[0];
    const float* Y  = (const float*)d_in[1];
    const float* sj = (const float*)d_in[2];
    const float* sx = (const float*)d_in[3];
    const float* sy = (const float*)d_in[4];
    float* out = (float*)d_out;
    char*  w   = (char*)d_ws;

    float* SQX  = (float*)(w + SQX_B);
    float* SQY  = (float*)(w + SQY_B);
    float* BSUM = (float*)(w + BSUM_B);
    float* COLS = (float*)(w + COL_B);
    float* ROWS = (float*)(w + ROW_B);
    unsigned short* XB = (unsigned short*)(w + XB_B);
    unsigned short* YB = (unsigned short*)(w + YB_B);

    if (ws_size >= (size_t)PRIMARY_NEED) {
        sq_kernel<true ><<<dim3(2048), dim3(256), 0, stream>>>(X, Y, SQX, SQY, XB, YB);
        kde_primary<<<dim3(NBLK), dim3(BLK), 0, stream>>>(XB, YB, sj, sx, sy, SQX, SQY, COLS, ROWS);
        lp_primary<<<dim3(64), dim3(128), 0, stream>>>(sj, sx, sy, COLS, ROWS, BSUM);
    } else {
        unsigned long long* ACC = (unsigned long long*)(w + ACC_B);
        hipMemsetAsync(w + ACC_B, 0, NROW * 3 * sizeof(unsigned long long), stream);
        sq_kernel<false><<<dim3(2048), dim3(256), 0, stream>>>(X, Y, SQX, SQY, XB, YB);
        kde_fb<<<dim3(NPAIR), dim3(FBLOCK), 0, stream>>>(X, Y, sj, sx, sy, ACC, SQX, SQY);
        lp_fb<<<dim3(64), dim3(128), 0, stream>>>(sj, sx, sy, ACC, BSUM);
    }
    final_reduce<<<dim3(1), dim3(64), 0, stream>>>(BSUM, out);
}